// Round 2
// baseline (405.889 us; speedup 1.0000x reference)
//
#include <hip/hip_runtime.h>
#include <hip/hip_bf16.h>

// Problem constants (B,T,H fixed by setup_inputs)
#define B_ 16
#define T_ 8192
#define H_ 256
#define M_ (B_ * T_)   // 131072 rows
#define STRIDE_ 8      // window over [max(0,t-8), t], count = min(t+1, 9)

typedef __bf16 bf16x8 __attribute__((ext_vector_type(8)));
typedef float f32x4 __attribute__((ext_vector_type(4)));

// round-to-nearest-even fp32 -> bf16 bits
__device__ __forceinline__ unsigned short f2bf(float f) {
  unsigned u = __builtin_bit_cast(unsigned, f);
  u += 0x7fffu + ((u >> 16) & 1u);
  return (unsigned short)(u >> 16);
}

// async global -> LDS, 16 bytes per lane (global_load_lds_dwordx4)
__device__ __forceinline__ void load_lds16(const void* g, void* l) {
  __builtin_amdgcn_global_load_lds(
      (const __attribute__((address_space(1))) void*)g,
      (__attribute__((address_space(3))) void*)l, 16, 0, 0);
}

// ---------------------------------------------------------------------------
// Kernel 1: build Wpk = 8 per-iteration swizzled LDS images of B^T, bf16.
// (unchanged)
// ---------------------------------------------------------------------------
__global__ __launch_bounds__(256) void wcat_kernel(
    const float* __restrict__ Wl, const float* __restrict__ bl,
    const float* __restrict__ Wm, const float* __restrict__ bm,
    unsigned short* __restrict__ Wpk, float* __restrict__ bias) {
  const int e = blockIdx.x * 256 + threadIdx.x;
  const int it = e >> 14;
  const int r = (e >> 6) & 255;
  const int col = e & 63;
  const int cp = col >> 3;
  const int ei = col & 7;
  const int c = cp ^ (r & 7);
  const int k = it * 32 + (c & 3) * 8 + ei + ((c < 4) ? 0 : 256);
  const float w = (k < 256) ? Wl[r * 256 + k] : Wm[r * 256 + (k - 256)];
  Wpk[e] = f2bf(w);
  if (e < 256) bias[e] = bl[e] + bm[e];
}

// ---------------------------------------------------------------------------
// Kernel 2 (fused): out[M,256] = [x | winmean(x)] @ Wcat^T + bias
// Change vs previous version: COUNTED-VMCNT RAW BARRIERS (T4). __syncthreads
// drains vmcnt(0) at every barrier, exposing ~900cy HBM latency of the x
// register prefetch each iteration. Now:
//   loop-top:  s_waitcnt lgkmcnt(0); s_barrier      (x loads stay in flight)
//   barrier2:  s_waitcnt vmcnt(12) lgkmcnt(0); s_barrier
//              (12 = younger x-prefetch loads; waits exactly the 8 B-glds)
// Issue order per iter: [8 B-glds][A-phase][12 x-prefetch][barrier2][MFMA].
// it==7 has no prefetch -> vmcnt(0) there (else glds would race ds_reads).
// setprio(1) wraps the MFMA cluster (T5: pays in role-split pipelines).
// grid: 2048 x 256
// ---------------------------------------------------------------------------
__global__ __launch_bounds__(256, 4) void fused_kernel(
    const float* __restrict__ x,            // [M, 256] fp32
    const unsigned short* __restrict__ Wpk, // 8 x [256][64] swizzled bf16
    const float* __restrict__ bias,         // [256]
    float* __restrict__ out) {              // [M, 256] fp32
  __shared__ __align__(16) unsigned short As[64 * 64];   //  8 KB swizzled
  __shared__ __align__(16) unsigned short Bs[256 * 64];  // 32 KB swizzled
  const int tid = threadIdx.x;
  const int m0 = blockIdx.x << 6;
  const int tb0 = m0 & (T_ - 1);   // token of tile row 0 within its batch
  const int w = tid >> 6;
  const int l = tid & 63;
  const int wc = w << 6;           // wave N offset (all waves share rows)
  const int lm = l & 15;
  const int kqc = l >> 4;          // k-chunk index within 32 (0..3)

  // A staging: col-pair p (16 pairs of 32-col chunk), row-group g (16 x 4 rows)
  const int p = tid & 15, g = tid >> 4;
  const float2* __restrict__ x2 = (const float2*)x;
  unsigned* __restrict__ As32 = (unsigned*)As;

  f32x4 acc[4][4];
#pragma unroll
  for (int i = 0; i < 4; ++i)
#pragma unroll
    for (int j = 0; j < 4; ++j) acc[i][j] = (f32x4){0.f, 0.f, 0.f, 0.f};

  // x-row register double buffer: 12 rows (8-row halo + 4 own) x float2
  float2 v[2][12];
  // prologue: issue it=0 window loads
#pragma unroll
  for (int i = 0; i < 12; ++i) {
    const int rl = (g << 2) - 8 + i;
    float2 val = {0.f, 0.f};
    if (tb0 + rl >= 0)                      // zero before batch start
      val = x2[(size_t)(m0 + rl) * 128 + p];
    v[0][i] = val;
  }

#pragma unroll
  for (int it = 0; it < 8; ++it) {
    // --- loop-top barrier: LDS ordering ONLY. x-prefetch stays in flight. ---
    asm volatile("s_waitcnt lgkmcnt(0)" ::: "memory");
    __builtin_amdgcn_s_barrier();
    __builtin_amdgcn_sched_barrier(0);

    // --- B: copy 32 KB pre-swizzled image (lane-linear, async). Issued
    //     FIRST so the counted vmcnt at barrier2 can target exactly these. ---
    const unsigned short* bsrc = Wpk + (it << 14);
#pragma unroll
    for (int rnd = 0; rnd < 8; ++rnd) {
      const int f = tid + (rnd << 8);
      load_lds16(bsrc + f * 8, &Bs[f * 8]);
    }
    __builtin_amdgcn_sched_barrier(0);  // glds issued before anything else

    // --- A: means from already-resident registers, emit x-pairs + mean-pairs
    float sx = 0.f, sy = 0.f;
#pragma unroll
    for (int i = 0; i < 8; ++i) {
      sx += v[it & 1][i].x;
      sy += v[it & 1][i].y;
    }
#pragma unroll
    for (int rr = 0; rr < 4; ++rr) {
      sx += v[it & 1][rr + 8].x;
      sy += v[it & 1][rr + 8].y;
      const int r = (g << 2) + rr;
      const int t = tb0 + r;
      const float inv =
          (t >= STRIDE_) ? (1.f / 9.f) : __builtin_amdgcn_rcpf((float)(t + 1));
      const unsigned xp = (unsigned)f2bf(v[it & 1][rr + 8].x) |
                          ((unsigned)f2bf(v[it & 1][rr + 8].y) << 16);
      const unsigned mp =
          (unsigned)f2bf(sx * inv) | ((unsigned)f2bf(sy * inv) << 16);
      const int sw = r & 7;
      As32[r * 32 + (((p >> 2) ^ sw) << 2) + (p & 3)] = xp;        // chunks 0-3
      As32[r * 32 + (((4 + (p >> 2)) ^ sw) << 2) + (p & 3)] = mp;  // chunks 4-7
      sx -= v[it & 1][rr].x;
      sy -= v[it & 1][rr].y;
    }

    // --- x prefetch for it+1: issued BEFORE barrier2 so it flies across
    //     MFMA + loop-top + next B-issue (~800cy of cover for ~900cy HBM) ---
    if (it < 7) {
#pragma unroll
      for (int i = 0; i < 12; ++i) {
        const int rl = (g << 2) - 8 + i;
        float2 val = {0.f, 0.f};
        if (tb0 + rl >= 0)
          val = x2[(size_t)(m0 + rl) * 128 + ((it + 1) << 4) + p];
        v[(it + 1) & 1][i] = val;
      }
    }
    __builtin_amdgcn_sched_barrier(0);  // prefetch issue pinned above the wait

    // --- barrier2: wait the 8 B-glds (oldest), keep 12 x loads in flight ---
    if (it < 7)
      asm volatile("s_waitcnt vmcnt(12) lgkmcnt(0)" ::: "memory");
    else
      asm volatile("s_waitcnt vmcnt(0) lgkmcnt(0)" ::: "memory");
    __builtin_amdgcn_s_barrier();
    __builtin_amdgcn_sched_barrier(0);

    // --- MFMA: K=64 in two k-steps of 32 ---
    __builtin_amdgcn_s_setprio(1);
#pragma unroll
    for (int kk = 0; kk < 2; ++kk) {
      const int cc = (kk << 2) + kqc;
      bf16x8 a[4], bb[4];
#pragma unroll
      for (int i = 0; i < 4; ++i) {
        const int R = (i << 4) + lm;
        a[i] = *(const bf16x8*)&As[R * 64 + ((cc ^ (R & 7)) << 3)];
      }
#pragma unroll
      for (int j = 0; j < 4; ++j) {
        const int R = wc + (j << 4) + lm;
        bb[j] = *(const bf16x8*)&Bs[R * 64 + ((cc ^ (R & 7)) << 3)];
      }
#pragma unroll
      for (int i = 0; i < 4; ++i)
#pragma unroll
        for (int j = 0; j < 4; ++j)
          acc[i][j] = __builtin_amdgcn_mfma_f32_16x16x32_bf16(a[i], bb[j],
                                                              acc[i][j], 0, 0, 0);
    }
    __builtin_amdgcn_s_setprio(0);
  }

  // epilogue: C/D layout col = l&15, row = (l>>4)*4 + reg
  const int r0 = (l >> 4) << 2;
#pragma unroll
  for (int j = 0; j < 4; ++j) {
    const int o = wc + (j << 4) + lm;
    const float bs = bias[o];
#pragma unroll
    for (int i = 0; i < 4; ++i) {
      const size_t mr = (size_t)(m0 + (i << 4) + r0);
#pragma unroll
      for (int r = 0; r < 4; ++r) out[(mr + r) * 256 + o] = acc[i][j][r] + bs;
    }
  }
}

// ---------------------------------------------------------------------------
extern "C" void kernel_launch(void* const* d_in, const int* in_sizes, int n_in,
                              void* d_out, int out_size, void* d_ws, size_t ws_size,
                              hipStream_t stream) {
  const float* x  = (const float*)d_in[0];
  const float* Wl = (const float*)d_in[1];
  const float* bl = (const float*)d_in[2];
  const float* Wm = (const float*)d_in[3];
  const float* bm = (const float*)d_in[4];
  float* out = (float*)d_out;

  // workspace: Wpk 8x256x64 bf16 (256 KiB) + bias 256 f32 (1 KiB)
  char* ws = (char*)d_ws;
  unsigned short* Wpk = (unsigned short*)ws;
  float* bias = (float*)(ws + (size_t)8 * 256 * 64 * 2);

  wcat_kernel<<<512, 256, 0, stream>>>(Wl, bl, Wm, bm, Wpk, bias);
  fused_kernel<<<2048, 256, 0, stream>>>(x, Wpk, bias, out);
}

// Round 3
// 271.377 us; speedup vs baseline: 1.4957x; 1.4957x over previous
//
#include <hip/hip_runtime.h>
#include <hip/hip_bf16.h>

// Problem constants (B,T,H fixed by setup_inputs)
#define B_ 16
#define T_ 8192
#define H_ 256
#define M_ (B_ * T_)   // 131072 rows
#define STRIDE_ 8      // window over [max(0,t-8), t], count = min(t+1, 9)

typedef __bf16 bf16x8 __attribute__((ext_vector_type(8)));
typedef float f32x4 __attribute__((ext_vector_type(4)));

// round-to-nearest-even fp32 -> bf16 bits
__device__ __forceinline__ unsigned short f2bf(float f) {
  unsigned u = __builtin_bit_cast(unsigned, f);
  u += 0x7fffu + ((u >> 16) & 1u);
  return (unsigned short)(u >> 16);
}

__device__ __forceinline__ unsigned pk2(float a, float b) {
  return (unsigned)f2bf(a) | ((unsigned)f2bf(b) << 16);
}

// ---------------------------------------------------------------------------
// Kernel 1: build Wpk = per-lane 16B B-fragments for direct global->reg loads.
// frag index e = ((it*2+kk)*16 + J)*64 + (kqc*16 + lm), lane part l=kqc*16+lm.
//   o = J*16+lm (out col), k = it*64 + (kk*4+kqc)*8 + e8  (K index, 0..511)
//   value = bf16( k<256 ? W_lin[o][k] : W_mem[o][k-256] )
// A wave (64 lanes) loading frag (it,kk,J) reads 1KB contiguous. 256 KiB total.
// ---------------------------------------------------------------------------
__global__ __launch_bounds__(256) void wcat_kernel(
    const float* __restrict__ Wl, const float* __restrict__ bl,
    const float* __restrict__ Wm, const float* __restrict__ bm,
    uint4* __restrict__ Wpk, float* __restrict__ bias) {
  const int e = blockIdx.x * 256 + threadIdx.x;  // 0..16383
  const int lm = e & 15;
  const int kqc = (e >> 4) & 3;
  const int J = (e >> 6) & 15;
  const int kk = (e >> 10) & 1;
  const int it = e >> 11;
  const int o = J * 16 + lm;
  const int k0 = it * 64 + (kk * 4 + kqc) * 8;
  float v[8];
#pragma unroll
  for (int e8 = 0; e8 < 8; ++e8) {
    const int k = k0 + e8;
    v[e8] = (k < 256) ? Wl[o * 256 + k] : Wm[o * 256 + (k - 256)];
  }
  uint4 fr;
  fr.x = pk2(v[0], v[1]);
  fr.y = pk2(v[2], v[3]);
  fr.z = pk2(v[4], v[5]);
  fr.w = pk2(v[6], v[7]);
  Wpk[e] = fr;
  if (e < 256) bias[e] = bl[e] + bm[e];
}

// ---------------------------------------------------------------------------
// Kernel 2 (fused): out[M,256] = [x | winmean(x)] @ Wcat^T + bias
// REDESIGN vs previous round (which sat at 2.5 TB/s effective = the roof of a
// 128B-granule gather pattern):
//  - Phase A: block stages its WHOLE A-tile once. Thread (cg,rg) reads 16 rows
//    x 8 cols (2x dwordx4/row; wave-level requests 512B-contiguous per row),
//    ring-sums the 9-row window in registers, writes bf16 [64][512] (x|mean)
//    A-tile to LDS, XOR-swizzled on 16B chunks (chunk ^= row&7).
//  - K-loop: NO BARRIERS. A-frags via ds_read_b128; B-frags double-buffered
//    registers direct from L2-hot Wpk (each wave's frag load = 1KB contig).
//  - Epilogue: acc -> LDS (reuse A-tile) -> full-row dwordx4 coalesced stores
//    (1KB per wave-instruction) to kill partial-line write inflation.
// LDS 64KB -> 2 blocks/CU; block n+1's stage overlaps block n's K-loop.
// grid: 2048 x 256
// ---------------------------------------------------------------------------
__global__ __launch_bounds__(256, 2) void fused_kernel(
    const float* __restrict__ x,        // [M, 256] fp32
    const uint4* __restrict__ Wpk,      // 16384 x 16B B-fragments (bf16)
    const float* __restrict__ bias,     // [256]
    float* __restrict__ out) {          // [M, 256] fp32
  __shared__ __align__(16) unsigned short As[64 * 512];  // 64 KB bf16 A-tile
  const int tid = threadIdx.x;
  // XCD-aware swizzle: 2048 % 8 == 0, contiguous 256-tile chunk per XCD.
  const int bid = (blockIdx.x & 7) * 256 + (blockIdx.x >> 3);
  const int m0 = bid << 6;
  const int tb0 = m0 & (T_ - 1);  // token of tile row 0 within its batch
  const int w = tid >> 6;
  const int l = tid & 63;
  const int wc = w << 6;
  const int lm = l & 15;
  const int kqc = l >> 4;

  uint4* As16 = (uint4*)As;  // 16B chunks, 64 per row

  // --- B it=0 prefetch (L2-hot after first blocks; oldest in vm queue) ---
  f32x4 bq0[8], bq1[8];
#pragma unroll
  for (int kk = 0; kk < 2; ++kk)
#pragma unroll
    for (int j = 0; j < 4; ++j)
      bq0[kk * 4 + j] =
          ((const f32x4*)Wpk)[((0 * 2 + kk) * 16 + (w * 4 + j)) * 64 + l];

  // --- Phase A: stage A-tile (x | windowed means), one pass over 16 rows ---
  {
    const int cg = tid & 31;   // col-group: f32 cols cg*8 .. cg*8+7
    const int rg = tid >> 5;   // row-group: out rows rg*8 .. rg*8+7
    const int c0 = cg << 3;
    f32x4 h[7][2];             // history rows 0..6 of the 16-row window
    f32x4 s0 = (f32x4){0.f, 0.f, 0.f, 0.f};
    f32x4 s1 = (f32x4){0.f, 0.f, 0.f, 0.f};
#pragma unroll
    for (int r = 0; r < 16; ++r) {
      const int lr = (rg << 3) - 8 + r;  // local row (-8 .. 63)
      f32x4 va = (f32x4){0.f, 0.f, 0.f, 0.f};
      f32x4 vb = (f32x4){0.f, 0.f, 0.f, 0.f};
      if (tb0 + lr >= 0) {               // zero before batch start
        const f32x4* xr = (const f32x4*)(x + (size_t)(m0 + lr) * 256 + c0);
        va = xr[0];
        vb = xr[1];
      }
      s0 += va;
      s1 += vb;
      if (r >= 9) { s0 -= h[r - 9][0]; s1 -= h[r - 9][1]; }
      if (r < 7) { h[r][0] = va; h[r][1] = vb; }
      if (r >= 8) {
        const int R = (rg << 3) + (r - 8);  // output local row 0..63
        const int t = tb0 + R;
        const float inv = (t >= STRIDE_)
                              ? (1.f / 9.f)
                              : __builtin_amdgcn_rcpf((float)(t + 1));
        // x-half: logical chunk q = cg (bf16 cols 8cg..8cg+7)
        uint4 xp;
        xp.x = pk2(va.x, va.y); xp.y = pk2(va.z, va.w);
        xp.z = pk2(vb.x, vb.y); xp.w = pk2(vb.z, vb.w);
        As16[R * 64 + (cg ^ (R & 7))] = xp;
        // mean-half: logical chunk q = 32+cg (bf16 cols 256+8cg ..)
        const f32x4 m0v = s0 * inv, m1v = s1 * inv;
        uint4 mp;
        mp.x = pk2(m0v.x, m0v.y); mp.y = pk2(m0v.z, m0v.w);
        mp.z = pk2(m1v.x, m1v.y); mp.w = pk2(m1v.z, m1v.w);
        As16[R * 64 + ((32 + cg) ^ (R & 7))] = mp;
      }
    }
  }
  __syncthreads();  // A-tile complete (also covers bq0 via its vmcnt use)

  // --- K-loop: 8 iterations of K=64, NO barriers ---
  f32x4 acc[4][4];
#pragma unroll
  for (int i = 0; i < 4; ++i)
#pragma unroll
    for (int j = 0; j < 4; ++j) acc[i][j] = (f32x4){0.f, 0.f, 0.f, 0.f};

#pragma unroll
  for (int it = 0; it < 8; ++it) {
    f32x4* cur = (it & 1) ? bq1 : bq0;
    f32x4* nxt = (it & 1) ? bq0 : bq1;
    if (it < 7) {
#pragma unroll
      for (int kk = 0; kk < 2; ++kk)
#pragma unroll
        for (int j = 0; j < 4; ++j)
          nxt[kk * 4 + j] =
              ((const f32x4*)Wpk)[(((it + 1) * 2 + kk) * 16 + (w * 4 + j)) * 64 + l];
    }
#pragma unroll
    for (int kk = 0; kk < 2; ++kk) {
      const int qa = it * 8 + kk * 4 + kqc;  // 16B chunk index in A row
      bf16x8 a[4];
#pragma unroll
      for (int i = 0; i < 4; ++i) {
        const int R = (i << 4) + lm;
        a[i] = ((const bf16x8*)As)[R * 64 + (qa ^ (R & 7))];
      }
#pragma unroll
      for (int i = 0; i < 4; ++i)
#pragma unroll
        for (int j = 0; j < 4; ++j)
          acc[i][j] = __builtin_amdgcn_mfma_f32_16x16x32_bf16(
              a[i], __builtin_bit_cast(bf16x8, cur[kk * 4 + j]), acc[i][j],
              0, 0, 0);
    }
  }

  // --- Epilogue: acc -> LDS (f32, reuse As) -> coalesced full-row stores ---
  __syncthreads();  // all ds_reads of A-tile done before overwrite
  float* Os = (float*)As;  // [64][256] f32, chunk-swizzled (16B chunks)
  const int r0 = kqc << 2;
#pragma unroll
  for (int j = 0; j < 4; ++j) {
    const int o = wc + (j << 4) + lm;
    const float bs = bias[o];
    const int qo = o >> 2, so = o & 3;
#pragma unroll
    for (int i = 0; i < 4; ++i) {
#pragma unroll
      for (int r = 0; r < 4; ++r) {
        const int row = (i << 4) + r0 + r;
        Os[row * 256 + ((qo ^ (row & 7)) << 2) + so] = acc[i][j][r] + bs;
      }
    }
  }
  __syncthreads();
#pragma unroll
  for (int k = 0; k < 16; ++k) {
    const int row = w + (k << 2);  // wave reads/stores a full 1KB row
    const f32x4 vv = ((const f32x4*)Os)[row * 64 + (l ^ (row & 7))];
    ((f32x4*)(out + (size_t)(m0 + row) * 256))[l] = vv;
  }
}

// ---------------------------------------------------------------------------
extern "C" void kernel_launch(void* const* d_in, const int* in_sizes, int n_in,
                              void* d_out, int out_size, void* d_ws, size_t ws_size,
                              hipStream_t stream) {
  const float* x  = (const float*)d_in[0];
  const float* Wl = (const float*)d_in[1];
  const float* bl = (const float*)d_in[2];
  const float* Wm = (const float*)d_in[3];
  const float* bm = (const float*)d_in[4];
  float* out = (float*)d_out;

  // workspace: Wpk 16384 x 16B (256 KiB) + bias 256 f32 (1 KiB)
  char* ws = (char*)d_ws;
  uint4* Wpk = (uint4*)ws;
  float* bias = (float*)(ws + (size_t)16384 * 16);

  wcat_kernel<<<64, 256, 0, stream>>>(Wl, bl, Wm, bm, Wpk, bias);
  fused_kernel<<<2048, 256, 0, stream>>>(x, Wpk, bias, out);
}